// Round 1
// 1970.316 us; speedup vs baseline: 1.1163x; 1.1163x over previous
//
#include <hip/hip_runtime.h>
#include <hip/hip_bf16.h>
#include <math.h>

#define N_TOK 8192
#define H_DIM 4096
#define V_DIM 32000
#define BM 128
#define BN 256
#define BK 128                     /* K-bytes per LDS tile (fp8: 1 B/elem) */
#define NCT (V_DIM / BN)           /* 125 col tiles */
#define NRT (N_TOK / BM)           /* 64 row tiles  */
#define NCHUNK 8
#define IGNORE_INDEX (-100)

typedef __attribute__((ext_vector_type(4))) int int4v;
typedef __attribute__((ext_vector_type(8))) int int8v;
typedef __attribute__((ext_vector_type(16))) float floatx16;
typedef unsigned int u32;
typedef unsigned short u16;
typedef unsigned char u8;

#define AS1 __attribute__((address_space(1)))
#define AS3 __attribute__((address_space(3)))

// ---------- fp32 -> OCP e4m3fn conversion ----------
__device__ __forceinline__ u32 f2e4m3_manual(float x) {
    u32 u = __float_as_uint(x);
    u32 s = (u >> 24) & 0x80u;
    u32 a = u & 0x7FFFFFFFu;
    if (a >= 0x43E00000u) return s | 0x7Eu;          // >= 448 -> saturate to 448
    int e = (int)(a >> 23) - 127;
    u32 mant = a & 0x7FFFFFu;
    if (e < -9) return s;                            // below half of min subnormal
    if (e >= -6) {                                   // normal range
        u32 m = mant >> 20;
        u32 rem = mant & 0xFFFFFu;
        u32 rnd = (rem > 0x80000u) || (rem == 0x80000u && (m & 1u));
        m += rnd;
        u32 E = (u32)(e + 7);
        if (m == 8u) { m = 0u; E += 1u; }
        if (E >= 16u) return s | 0x7Eu;
        return s | (E << 3) | m;
    } else {                                         // subnormal: m * 2^-9
        int drop = 20 + (-6 - e);
        u32 full = 0x800000u | mant;
        u32 m = full >> drop;
        u32 rem = full & ((1u << drop) - 1u);
        u32 half = 1u << (drop - 1);
        u32 rnd = (rem > half) || (rem == half && (m & 1u));
        m += rnd;
        return s | m;                                // m==8 -> 0x08 == min normal, correct
    }
}

__device__ __forceinline__ u32 pk4_fp8(float a, float b, float c, float d) {
#if __has_builtin(__builtin_amdgcn_cvt_pk_fp8_f32)
    int v = __builtin_amdgcn_cvt_pk_fp8_f32(a, b, 0, false);
    v = __builtin_amdgcn_cvt_pk_fp8_f32(c, d, v, true);
    return (u32)v;
#else
    return f2e4m3_manual(a) | (f2e4m3_manual(b) << 8) |
           (f2e4m3_manual(c) << 16) | (f2e4m3_manual(d) << 24);
#endif
}

// fp32 -> fp8 with static scale; 8 elements / thread, 16B loads, 8B stores
__global__ void cvt_fp8_kernel(const float4* __restrict__ src, uint2* __restrict__ dst,
                               int n8, float scale) {
    int i = blockIdx.x * blockDim.x + threadIdx.x;
    int stride = gridDim.x * blockDim.x;
    for (; i < n8; i += stride) {
        float4 a = src[2 * i], b = src[2 * i + 1];
        uint2 o;
        o.x = pk4_fp8(a.x * scale, a.y * scale, a.z * scale, a.w * scale);
        o.y = pk4_fp8(b.x * scale, b.y * scale, b.z * scale, b.w * scale);
        dst[i] = o;
    }
}

// ---------- fused MX-fp8 GEMM-BT + online-softmax partials ----------
// 128x256 tile, BK=128 bytes, 4 waves in 2x2, each wave 64x128 via 2x4 of
// mfma_scale_f32_32x32x64_f8f6f4 (fragment reuse: 12 ds_read feed 8 MFMA,
// was 8:4 -> 25% fewer LDS reads/MFMA + half the epilogue shfl per output).
// Constant e8m0 scales: A=1.0 (0x7F), B=2^-6 (0x79) undoing the x64 applied
// during weight conversion.
// Grid is rowT-fast: consecutive blocks share the W tile and stream A
// (33.5 MB, L3-resident after first sweep); W (131 MB) is fetched from HBM
// exactly once instead of 64x.
// LDS rows are 128 B = 8 x 16B blocks, staged via global_load_lds(16B) with
// XOR swizzle jdst = jsrc ^ (row&7) -> ds_read_b128 conflict-free.
__global__ __launch_bounds__(256, 2) void gemm_lse_kernel(
    const u8* __restrict__ A,       // [N_TOK][H_DIM] fp8
    const u8* __restrict__ W,       // [V_DIM][H_DIM] fp8 (x64)
    const int* __restrict__ tgt,
    float2* __restrict__ partials,  // [NCT][N_TOK] (m, l)
    float* __restrict__ tlogit)     // [N_TOK]
{
    __shared__ __attribute__((aligned(16))) u8 lds_a[BM * BK];   // 16 KB
    __shared__ __attribute__((aligned(16))) u8 lds_b[BN * BK];   // 32 KB
    __shared__ float red_m[BM][2];
    __shared__ float red_l[BM][2];
    __shared__ int tgt_s[BM];

    const int bid = blockIdx.x;
    const int rowT = bid & (NRT - 1);    // row-fast (NRT=64 is pow2)
    const int colT = bid >> 6;
    const int row0 = rowT * BM;
    const int col0 = colT * BN;

    const int tid = threadIdx.x;
    const int lane = tid & 63;
    const int wv = tid >> 6;
    const int m = lane & 31;
    const int kh = lane >> 5;            // k-half within MFMA operand
    const int wr = wv >> 1;              // wave row: 0..1 (64 rows each)
    const int wc = wv & 1;               // wave col: 0..1 (128 cols each)

    if (tid < BM) tgt_s[tid] = tgt[row0 + tid];

    floatx16 acc[2][4];
#pragma unroll
    for (int i = 0; i < 2; ++i)
#pragma unroll
        for (int j = 0; j < 4; ++j)
#pragma unroll
            for (int r = 0; r < 16; ++r) acc[i][j][r] = 0.f;

    const u8* Ab = A + (size_t)row0 * H_DIM;
    const u8* Bb = W + (size_t)col0 * H_DIM;

    const int rsub = lane >> 3;          // 0..7 row within 8-row staging chunk
    const int jdst = lane & 7;           // dest 16B block within 128B row
    const int jsrc16 = (jdst ^ rsub) * 16;   // R&7 == rsub for 8-aligned chunks

    for (int k0 = 0; k0 < H_DIM; k0 += BK) {
        __syncthreads();
        // 48 chunks of 8 rows: 16 for A (16 KB), 32 for B (32 KB); 12/wave.
#pragma unroll
        for (int t = 0; t < 12; ++t) {
            int c = wv * 12 + t;
            if (c < 16) {
                int R = c * 8 + rsub;
                const u8* ga = Ab + (size_t)R * H_DIM + (k0 + jsrc16);
                __builtin_amdgcn_global_load_lds((AS1 const u32*)ga, (AS3 u32*)&lds_a[c * 1024], 16, 0, 0);
            } else {
                int cc = c - 16;
                int R = cc * 8 + rsub;
                const u8* gb = Bb + (size_t)R * H_DIM + (k0 + jsrc16);
                __builtin_amdgcn_global_load_lds((AS1 const u32*)gb, (AS3 u32*)&lds_b[cc * 1024], 16, 0, 0);
            }
        }
        __syncthreads();
#pragma unroll
        for (int kk = 0; kk < 2; ++kk) {
            const int b0 = kk * 4 + kh * 2;      // lane's first 16B k-block
            const int sw = m & 7;
            int8v af[2], bf[4];
#pragma unroll
            for (int i = 0; i < 2; ++i) {
                const u8* base = &lds_a[(wr * 64 + i * 32 + m) * BK];
                int4v lo = *(const int4v*)(base + ((b0) ^ sw) * 16);
                int4v hi = *(const int4v*)(base + ((b0 + 1) ^ sw) * 16);
                af[i] = __builtin_shufflevector(lo, hi, 0, 1, 2, 3, 4, 5, 6, 7);
            }
#pragma unroll
            for (int j = 0; j < 4; ++j) {
                const u8* base = &lds_b[(wc * 128 + j * 32 + m) * BK];
                int4v lo = *(const int4v*)(base + ((b0) ^ sw) * 16);
                int4v hi = *(const int4v*)(base + ((b0 + 1) ^ sw) * 16);
                bf[j] = __builtin_shufflevector(lo, hi, 0, 1, 2, 3, 4, 5, 6, 7);
            }
#pragma unroll
            for (int i = 0; i < 2; ++i)
#pragma unroll
                for (int j = 0; j < 4; ++j)
                    acc[i][j] = __builtin_amdgcn_mfma_scale_f32_32x32x64_f8f6f4(
                        af[i], bf[j], acc[i][j], 0, 0,   // cbsz=fp8, blgp=fp8
                        0, 0x7F7F7F7F,                   // scale A = 1.0
                        0, 0x79797979);                  // scale B = 2^-6
        }
    }

    // Epilogue. C/D layout (32x32, shape-determined): col = lane&31,
    // row = (reg&3) + 8*(reg>>2) + 4*(lane>>5). Fold the 4 j-tiles on the
    // VALU first, then one 10-shfl butterfly covers 128 columns.
#pragma unroll
    for (int i = 0; i < 2; ++i) {
#pragma unroll
        for (int r = 0; r < 16; ++r) {
            float v0 = acc[i][0][r], v1 = acc[i][1][r];
            float v2 = acc[i][2][r], v3 = acc[i][3][r];
            int rloc = wr * 64 + i * 32 + (r & 3) + 8 * (r >> 2) + 4 * kh;
            int t = tgt_s[rloc];
            int cbase = col0 + wc * 128 + m;
            if (t == cbase)      tlogit[row0 + rloc] = v0;
            if (t == cbase + 32) tlogit[row0 + rloc] = v1;
            if (t == cbase + 64) tlogit[row0 + rloc] = v2;
            if (t == cbase + 96) tlogit[row0 + rloc] = v3;
            float mx = fmaxf(fmaxf(v0, v1), fmaxf(v2, v3));
#pragma unroll
            for (int d = 1; d < 32; d <<= 1) mx = fmaxf(mx, __shfl_xor(mx, d, 64));
            float s = __expf(v0 - mx) + __expf(v1 - mx) + __expf(v2 - mx) + __expf(v3 - mx);
#pragma unroll
            for (int d = 1; d < 32; d <<= 1) s += __shfl_xor(s, d, 64);
            if (m == 0) { red_m[rloc][wc] = mx; red_l[rloc][wc] = s; }
        }
    }
    __syncthreads();
    if (tid < BM) {
        float m0 = red_m[tid][0], m1 = red_m[tid][1];
        float M = fmaxf(m0, m1);
        float L = red_l[tid][0] * __expf(m0 - M) + red_l[tid][1] * __expf(m1 - M);
        partials[(size_t)colT * N_TOK + row0 + tid] = make_float2(M, L);
    }
}

// ---------- two-stage partial merge ----------
__global__ void reduce1_kernel(const float2* __restrict__ partials, float2* __restrict__ part2) {
    int gid = blockIdx.x * blockDim.x + threadIdx.x;   // 0..65535
    int row = gid & (N_TOK - 1);
    int chunk = gid >> 13;                             // 0..7
    int c0 = (chunk * NCT) / NCHUNK;
    int c1 = ((chunk + 1) * NCT) / NCHUNK;
    float M = -INFINITY, L = 0.f;
    for (int ct = c0; ct < c1; ++ct) {
        float2 p = partials[(size_t)ct * N_TOK + row];
        float nm = fmaxf(M, p.x);
        L = L * __expf(M - nm) + p.y * __expf(p.x - nm);
        M = nm;
    }
    part2[gid] = make_float2(M, L);
}

__global__ void reduce2_kernel(const float2* __restrict__ part2,
                               const float* __restrict__ tlogit,
                               const int* __restrict__ tgt,
                               float* __restrict__ accum) {
    int row = blockIdx.x * blockDim.x + threadIdx.x;
    float nll = 0.f, cnt = 0.f;
    if (row < N_TOK) {
        float M = -INFINITY, L = 0.f;
#pragma unroll
        for (int c = 0; c < NCHUNK; ++c) {
            float2 p = part2[c * N_TOK + row];
            float nm = fmaxf(M, p.x);
            L = L * __expf(M - nm) + p.y * __expf(p.x - nm);
            M = nm;
        }
        if (tgt[row] != IGNORE_INDEX) {
            nll = M + __logf(L) - tlogit[row];
            cnt = 1.f;
        }
    }
#pragma unroll
    for (int d = 32; d > 0; d >>= 1) {
        nll += __shfl_down(nll, d, 64);
        cnt += __shfl_down(cnt, d, 64);
    }
    if ((threadIdx.x & 63) == 0) {
        atomicAdd(&accum[0], nll);
        atomicAdd(&accum[1], cnt);
    }
}

__global__ void finalize_kernel(const float* __restrict__ accum, float* __restrict__ out) {
    out[0] = accum[0] / fmaxf(accum[1], 1.f);
}

extern "C" void kernel_launch(void* const* d_in, const int* in_sizes, int n_in,
                              void* d_out, int out_size, void* d_ws, size_t ws_size,
                              hipStream_t stream) {
    (void)in_sizes; (void)n_in; (void)out_size; (void)ws_size;
    const float* input = (const float*)d_in[0];   // [8192, 4096] fp32
    const float* weight = (const float*)d_in[1];  // [32000, 4096] fp32
    const int* target = (const int*)d_in[2];      // [8192] int
    float* out = (float*)d_out;

    // workspace layout (bytes):
    //   [0,          33554432)   A fp8   (8192*4096)
    //   [33554432,  164626432)   W fp8   (32000*4096)
    //   [164626432, 172818432)   partials float2 [125][8192]
    //   [172818432, 173342720)   part2 float2 [8][8192]
    //   [173342720, 173375488)   tlogit float [8192]
    //   [173375488, 173375496)   accum {sum, count}
    char* ws = (char*)d_ws;
    u8* Afp8 = (u8*)ws;
    u8* Wfp8 = (u8*)(ws + 33554432);
    float2* partials = (float2*)(ws + 164626432);
    float2* part2 = (float2*)(ws + 172818432);
    float* tlogit = (float*)(ws + 173342720);
    float* accum = (float*)(ws + 173375488);

    hipMemsetAsync(accum, 0, 2 * sizeof(float), stream);

    cvt_fp8_kernel<<<4096, 256, 0, stream>>>((const float4*)input, (uint2*)Afp8,
                                             N_TOK * H_DIM / 8, 1.0f);
    cvt_fp8_kernel<<<8192, 256, 0, stream>>>((const float4*)weight, (uint2*)Wfp8,
                                             V_DIM * H_DIM / 8, 64.0f);

    gemm_lse_kernel<<<NRT * NCT, 256, 0, stream>>>(Afp8, Wfp8, target, partials, tlogit);

    reduce1_kernel<<<NCHUNK * N_TOK / 256, 256, 0, stream>>>(partials, part2);
    reduce2_kernel<<<N_TOK / 256, 256, 0, stream>>>(part2, tlogit, target, accum);
    finalize_kernel<<<1, 1, 0, stream>>>(accum, out);
}